// Round 2
// baseline (553.547 us; speedup 1.0000x reference)
//
#include <hip/hip_runtime.h>
#include <math.h>

#define HWSZ 4096   // 64*64
#define DIM  64
#define KCW  512
#define NROW 131072 // 32*4096
#define RPB  256    // rows per block (512 threads, 2 k-planes)

// ws layout (floats): ws[0] = loss accumulator; ws[64 .. 64+512) = c_sq
__global__ void vq_prep_kernel(const float* __restrict__ cw, float* __restrict__ ws) {
    int k = blockIdx.x * blockDim.x + threadIdx.x;
    if (k == 0) ws[0] = 0.f;
    if (k < KCW) {
        float s = 0.f;
        #pragma unroll
        for (int d = 0; d < DIM; ++d) { float c = cw[k * DIM + d]; s = fmaf(c, c, s); }
        ws[64 + k] = s;
    }
}

__global__ __launch_bounds__(512, 4) void vq_main_kernel(const float* __restrict__ in,
                                                         const float* __restrict__ cw,
                                                         float* __restrict__ out,
                                                         float* __restrict__ ws) {
    __shared__ float sbest[512];
    __shared__ int   sidx[512];

    const float* __restrict__ c_sq = ws + 64;
    const int t     = threadIdx.x;
    const int plane = t >> 8;          // 0: k<256, 1: k>=256 (wave-uniform)
    const int r     = t & 255;
    const int row   = blockIdx.x * RPB + r;
    const int b     = row >> 12;
    const int hw    = row & (HWSZ - 1);

    const float* __restrict__ xin = in + (size_t)b * (DIM * HWSZ) + hw;
    float x[DIM];
    #pragma unroll
    for (int d = 0; d < DIM; ++d) x[d] = xin[(size_t)d * HWSZ];

    float x_sq = 0.f;
    #pragma unroll
    for (int d = 0; d < DIM; ++d) x_sq = fmaf(x[d], x[d], x_sq);

    float best = INFINITY;
    int bestk = 0;
    const int k0 = plane << 8;
    for (int k = k0; k < k0 + 256; ++k) {
        const float4* __restrict__ c4 = (const float4*)(cw + (size_t)k * DIM);
        float d0 = 0.f, d1 = 0.f, d2 = 0.f, d3 = 0.f;
        #pragma unroll
        for (int i = 0; i < DIM / 4; ++i) {
            float4 c = c4[i];
            d0 = fmaf(x[4 * i + 0], c.x, d0);
            d1 = fmaf(x[4 * i + 1], c.y, d1);
            d2 = fmaf(x[4 * i + 2], c.z, d2);
            d3 = fmaf(x[4 * i + 3], c.w, d3);
        }
        float dot = (d0 + d1) + (d2 + d3);
        // mirror reference rounding: (x_sq + c_sq) - 2*dot
        float dist = (x_sq + c_sq[k]) - 2.f * dot;
        if (dist < best) { best = dist; bestk = k; }  // strict <: first index wins ties
    }

    sbest[t] = best;
    sidx[t]  = bestk;
    __syncthreads();

    if (t < 256) {
        // plane-0 priority on ties (lower k wins) -> strict < for plane 1
        float b1 = sbest[t + 256];
        if (b1 < best) bestk = sidx[t + 256];
        sidx[t] = bestk;
        out[(size_t)NROW * DIM + row] = (float)bestk;   // indices chunk
    }
    __syncthreads();

    const int kw = sidx[r];
    const float* __restrict__ q = cw + (size_t)kw * DIM;
    float* __restrict__ xout = out + (size_t)b * (DIM * HWSZ) + hw;

    float lsum = 0.f;
    if (plane == 0) {   // wave-uniform branch; static x[] indices in both arms
        #pragma unroll
        for (int i = 0; i < 32; ++i) {
            float qd = q[i];
            xout[(size_t)i * HWSZ] = qd;
            float diff = qd - x[i];
            lsum = fmaf(diff, diff, lsum);
        }
    } else {
        #pragma unroll
        for (int i = 0; i < 32; ++i) {
            float qd = q[32 + i];
            xout[(size_t)(32 + i) * HWSZ] = qd;
            float diff = qd - x[32 + i];
            lsum = fmaf(diff, diff, lsum);
        }
    }

    // wave-level reduce then one atomic per wave
    #pragma unroll
    for (int off = 32; off; off >>= 1) lsum += __shfl_down(lsum, off, 64);
    if ((threadIdx.x & 63) == 0) atomicAdd(ws, lsum);
}

__global__ void vq_finalize_kernel(const float* __restrict__ ws, float* __restrict__ out) {
    // loss = (1 + 0.25) * mean((q - x)^2) over B*H*W*D elements
    out[(size_t)NROW * DIM + NROW] = 1.25f * ws[0] / (float)((size_t)NROW * DIM);
}

extern "C" void kernel_launch(void* const* d_in, const int* in_sizes, int n_in,
                              void* d_out, int out_size, void* d_ws, size_t ws_size,
                              hipStream_t stream) {
    const float* in = (const float*)d_in[0];
    const float* cw = (const float*)d_in[1];
    float* out = (float*)d_out;
    float* ws  = (float*)d_ws;

    hipLaunchKernelGGL(vq_prep_kernel, dim3(2), dim3(256), 0, stream, cw, ws);
    hipLaunchKernelGGL(vq_main_kernel, dim3(NROW / RPB), dim3(512), 0, stream, in, cw, out, ws);
    hipLaunchKernelGGL(vq_finalize_kernel, dim3(1), dim3(1), 0, stream, ws, out);
}